// Round 2
// baseline (1117.137 us; speedup 1.0000x reference)
//
#include <hip/hip_runtime.h>
#include <cmath>

#define T_SIZE (1u << 19)

typedef _Float16 h8 __attribute__((ext_vector_type(8)));
typedef _Float16 h2 __attribute__((ext_vector_type(2)));
typedef float f4 __attribute__((ext_vector_type(4)));

struct Levels {
    float scale[16];
    int   res[16];
    unsigned dense_mask;
};

// softplus(10z)/10 via hardware exp2/log2
__device__ __forceinline__ float softplus10(float z) {
    float y = z * 10.0f;
    float t = __builtin_amdgcn_exp2f(y * 1.4426950408889634f);          // e^y
    float sp = __builtin_amdgcn_logf(1.0f + t) * 0.069314718055994531f; // ln(1+e^y)/10
    return (y > 20.0f) ? z : sp;
}

// ---------------- Kernel A: hash-grid encode -> f16 [N][32] ----------------
// One thread per (point, level): 16M threads, 8 independent gathers each.
// Low VGPR => high occupancy => many loads in flight (gather-latency bound fix).
__global__ __launch_bounds__(256) void encode_kernel(
    const float* __restrict__ xs, const float* __restrict__ table,
    _Float16* __restrict__ enc, Levels lv, int N)
{
    __shared__ float s_scale[16];
    __shared__ int   s_res[16];
    __shared__ float sx[48];                       // 16 points * xyz

    const int p0 = blockIdx.x * 16;                // 16 points per block
    if (threadIdx.x < 16) {
        s_scale[threadIdx.x] = lv.scale[threadIdx.x];
        s_res[threadIdx.x]   = lv.res[threadIdx.x];
    }
    if (threadIdx.x < 48) sx[threadIdx.x] = xs[(size_t)p0 * 3 + threadIdx.x];
    __syncthreads();

    const int pi = threadIdx.x >> 4;               // local point 0..15
    const int l  = threadIdx.x & 15;               // level 0..15
    const int i  = p0 + pi;
    if (i >= N) return;

    const float px = sx[3 * pi + 0], py = sx[3 * pi + 1], pz = sx[3 * pi + 2];
    const float s  = s_scale[l];
    const int  res = s_res[l];

    float fx = px * s + 0.5f, fy = py * s + 0.5f, fz = pz * s + 0.5f;
    float gx = floorf(fx), gy = floorf(fy), gz = floorf(fz);
    float wx = fx - gx, wy = fy - gy, wz = fz - gz;
    int cx = (int)gx, cy = (int)gy, cz = (int)gz;

    unsigned idx[8];
    if ((lv.dense_mask >> l) & 1u) {
        int r1 = res - 1;
        int x0 = min(cx, r1), x1 = min(cx + 1, r1);
        int y0 = min(cy, r1), y1 = min(cy + 1, r1);
        int z0 = min(cz, r1), z1 = min(cz + 1, r1);
        int yr0 = y0 * res, yr1 = y1 * res;
        int rr = res * res;
        int zr0 = z0 * rr, zr1 = z1 * rr;
        idx[0] = x0 + yr0 + zr0;
        idx[1] = x0 + yr0 + zr1;
        idx[2] = x0 + yr1 + zr0;
        idx[3] = x0 + yr1 + zr1;
        idx[4] = x1 + yr0 + zr0;
        idx[5] = x1 + yr0 + zr1;
        idx[6] = x1 + yr1 + zr0;
        idx[7] = x1 + yr1 + zr1;
    } else {
        unsigned hx0 = (unsigned)cx, hx1 = (unsigned)(cx + 1);
        unsigned hy0 = (unsigned)cy * 2654435761u, hy1 = (unsigned)(cy + 1) * 2654435761u;
        unsigned hz0 = (unsigned)cz * 805459861u,  hz1 = (unsigned)(cz + 1) * 805459861u;
        idx[0] = (hx0 ^ hy0 ^ hz0) & (T_SIZE - 1);
        idx[1] = (hx0 ^ hy0 ^ hz1) & (T_SIZE - 1);
        idx[2] = (hx0 ^ hy1 ^ hz0) & (T_SIZE - 1);
        idx[3] = (hx0 ^ hy1 ^ hz1) & (T_SIZE - 1);
        idx[4] = (hx1 ^ hy0 ^ hz0) & (T_SIZE - 1);
        idx[5] = (hx1 ^ hy0 ^ hz1) & (T_SIZE - 1);
        idx[6] = (hx1 ^ hy1 ^ hz0) & (T_SIZE - 1);
        idx[7] = (hx1 ^ hy1 ^ hz1) & (T_SIZE - 1);
    }

    const float2* tl = ((const float2*)table) + (size_t)l * T_SIZE;
    float2 v0 = tl[idx[0]], v1 = tl[idx[1]], v2 = tl[idx[2]], v3 = tl[idx[3]];
    float2 v4 = tl[idx[4]], v5 = tl[idx[5]], v6 = tl[idx[6]], v7 = tl[idx[7]];

    float wx0 = 1.f - wx, wy0 = 1.f - wy, wz0 = 1.f - wz;
    float wxy00 = wx0 * wy0, wxy01 = wx0 * wy, wxy10 = wx * wy0, wxy11 = wx * wy;
    float f0 = 0.f, f1 = 0.f, wc;
    wc = wxy00 * wz0; f0 += wc * v0.x; f1 += wc * v0.y;
    wc = wxy00 * wz;  f0 += wc * v1.x; f1 += wc * v1.y;
    wc = wxy01 * wz0; f0 += wc * v2.x; f1 += wc * v2.y;
    wc = wxy01 * wz;  f0 += wc * v3.x; f1 += wc * v3.y;
    wc = wxy10 * wz0; f0 += wc * v4.x; f1 += wc * v4.y;
    wc = wxy10 * wz;  f0 += wc * v5.x; f1 += wc * v5.y;
    wc = wxy11 * wz0; f0 += wc * v6.x; f1 += wc * v6.y;
    wc = wxy11 * wz;  f0 += wc * v7.x; f1 += wc * v7.y;

    h2 r;
    r[0] = (_Float16)f0;
    r[1] = (_Float16)f1;
    *(h2*)(enc + (size_t)i * 32 + 2 * l) = r;     // 4B store, wave-contiguous
}

// ---------------- Kernel B: fused MLP via f16 MFMA ----------------
// 512 persistent-ish blocks (2/CU), each loops `tiles` tiles of 256 points.
// A-layout: A[m=lane&15][k=quad*8+j]; D-layout: D[row=quad*4+r][col=lane&15].
__global__ __launch_bounds__(256) void mlp_kernel(
    const _Float16* __restrict__ enc,
    const float* __restrict__ w1, const float* __restrict__ w2,
    const float* __restrict__ w3, const float* __restrict__ w4,
    float* __restrict__ out, int tiles)
{
    constexpr int W1R = 40;
    constexpr int W2R = 72;
    constexpr int AR  = 72;
    __shared__ _Float16 sW1[64 * W1R];
    __shared__ _Float16 sW2[64 * W2R];
    __shared__ _Float16 sW3[64 * W2R];
    __shared__ float    sW4[64];
    __shared__ _Float16 sAct[256 * AR];

    const int tid = threadIdx.x;
    for (int i = tid; i < 64 * 32; i += 256) sW1[(i >> 5) * W1R + (i & 31)] = (_Float16)w1[i];
    for (int i = tid; i < 64 * 64; i += 256) sW2[(i >> 6) * W2R + (i & 63)] = (_Float16)w2[i];
    for (int i = tid; i < 64 * 64; i += 256) sW3[(i >> 6) * W2R + (i & 63)] = (_Float16)w3[i];
    if (tid < 64) sW4[tid] = w4[tid];
    __syncthreads();

    const int wave = tid >> 6;
    const int lane = tid & 63;
    const int lrow = lane & 15;
    const int quad = lane >> 4;
    const int waveRow = wave * 64;
    const f4 zero = {0.f, 0.f, 0.f, 0.f};

    // weight fragments (loop-invariant) — hoisted out of the tile loop
    h8 b1[4];
#pragma unroll
    for (int tn = 0; tn < 4; ++tn)
        b1[tn] = *(const h8*)&sW1[(lrow + 16 * tn) * W1R + quad * 8];
    h8 b2[2][4], b3[2][4];
#pragma unroll
    for (int kh = 0; kh < 2; ++kh)
#pragma unroll
        for (int tn = 0; tn < 4; ++tn) {
            b2[kh][tn] = *(const h8*)&sW2[(lrow + 16 * tn) * W2R + kh * 32 + quad * 8];
            b3[kh][tn] = *(const h8*)&sW3[(lrow + 16 * tn) * W2R + kh * 32 + quad * 8];
        }

    for (int it = 0; it < tiles; ++it) {
        const int blockPt = (blockIdx.x * tiles + it) * 256;

        // ---- Layer 1: enc(global f16 [N][32]) @ w1^T ----
#pragma unroll
        for (int t = 0; t < 4; ++t) {
            const size_t rowg = (size_t)(blockPt + waveRow + t * 16 + lrow);
            h8 a = *(const h8*)(enc + rowg * 32 + quad * 8);
#pragma unroll
            for (int tn = 0; tn < 4; ++tn) {
                f4 acc = __builtin_amdgcn_mfma_f32_16x16x32_f16(a, b1[tn], zero, 0, 0, 0);
#pragma unroll
                for (int r = 0; r < 4; ++r) {
                    int prow = waveRow + t * 16 + quad * 4 + r;
                    sAct[prow * AR + tn * 16 + lrow] = (_Float16)softplus10(acc[r]);
                }
            }
        }
        __syncthreads();

        // ---- Layers 2 & 3 ----
#pragma unroll
        for (int layer = 0; layer < 2; ++layer) {
#pragma unroll
            for (int t = 0; t < 4; ++t) {
                const int arow = (waveRow + t * 16 + lrow) * AR;
                h8 a0 = *(const h8*)&sAct[arow + quad * 8];
                h8 a1 = *(const h8*)&sAct[arow + 32 + quad * 8];
                f4 accs[4];
#pragma unroll
                for (int tn = 0; tn < 4; ++tn) {
                    f4 acc = __builtin_amdgcn_mfma_f32_16x16x32_f16(
                        a0, layer ? b3[0][tn] : b2[0][tn], zero, 0, 0, 0);
                    acc = __builtin_amdgcn_mfma_f32_16x16x32_f16(
                        a1, layer ? b3[1][tn] : b2[1][tn], acc, 0, 0, 0);
                    accs[tn] = acc;
                }
#pragma unroll
                for (int tn = 0; tn < 4; ++tn)
#pragma unroll
                    for (int r = 0; r < 4; ++r)
                        sAct[(waveRow + t * 16 + quad * 4 + r) * AR + tn * 16 + lrow] =
                            (_Float16)softplus10(accs[tn][r]);
            }
            __syncthreads();
        }

        // ---- Layer 4: per-thread dot with w4 ----
        float sum = 0.f;
#pragma unroll
        for (int k8 = 0; k8 < 8; ++k8) {
            h8 a = *(const h8*)&sAct[tid * AR + k8 * 8];
#pragma unroll
            for (int j = 0; j < 8; ++j) sum += (float)a[j] * sW4[k8 * 8 + j];
        }
        out[blockPt + tid] = sum;
        __syncthreads();   // sAct reused next iteration
    }
}

extern "C" void kernel_launch(void* const* d_in, const int* in_sizes, int n_in,
                              void* d_out, int out_size, void* d_ws, size_t ws_size,
                              hipStream_t stream) {
    const float* x     = (const float*)d_in[0];
    const float* table = (const float*)d_in[1];
    const float* w1    = (const float*)d_in[2];
    const float* w2    = (const float*)d_in[3];
    const float* w3    = (const float*)d_in[4];
    const float* w4    = (const float*)d_in[5];
    float* out = (float*)d_out;
    const int N = in_sizes[0] / 3;           // 1<<20
    _Float16* enc = (_Float16*)d_ws;         // N*32 f16 = 64 MB scratch

    Levels lv;
    lv.dense_mask = 0;
    const double pls = exp2(log2(2048.0 / 16.0) / 15.0);
    const double lg  = log2(pls);
    for (int l = 0; l < 16; ++l) {
        double sc = exp2((double)l * lg) * 16.0 - 1.0;
        int res = (int)ceil(sc) + 1;
        lv.scale[l] = (float)sc;
        lv.res[l]   = res;
        if ((long long)res * res * res <= (long long)T_SIZE) lv.dense_mask |= (1u << l);
    }

    const int encBlocks = (N * 16 + 255) / 256;  // one thread per (point, level)
    hipLaunchKernelGGL(encode_kernel, dim3(encBlocks), dim3(256), 0, stream,
                       x, table, enc, lv, N);

    const int mlpBlocks = 512;                   // 2 blocks/CU exactly
    const int tiles = N / 256 / mlpBlocks;       // 8
    hipLaunchKernelGGL(mlp_kernel, dim3(mlpBlocks), dim3(256), 0, stream,
                       enc, w1, w2, w3, w4, out, tiles);
}

// Round 3
// 670.425 us; speedup vs baseline: 1.6663x; 1.6663x over previous
//
#include <hip/hip_runtime.h>
#include <cmath>

#define T_SIZE (1u << 19)

typedef _Float16 h8 __attribute__((ext_vector_type(8)));
typedef _Float16 h2 __attribute__((ext_vector_type(2)));
typedef float f4 __attribute__((ext_vector_type(4)));

struct Levels {
    float scale[16];
    int   res[16];
    unsigned dense_mask;
};

// softplus(10z)/10 via hardware exp2/log2
__device__ __forceinline__ float softplus10(float z) {
    float y = z * 10.0f;
    float t = __builtin_amdgcn_exp2f(y * 1.4426950408889634f);          // e^y
    float sp = __builtin_amdgcn_logf(1.0f + t) * 0.069314718055994531f; // ln(1+e^y)/10
    return (y > 20.0f) ? z : sp;
}

__device__ __forceinline__ float2 load_pair(const float2* p) { return *p; }
__device__ __forceinline__ float2 load_pair(const h2* p) {
    h2 v = *p;
    return make_float2((float)v[0], (float)v[1]);
}

// -------- Kernel 0: table f32 -> f16 pairs (one 4B entry per table slot) ----
__global__ __launch_bounds__(256) void convert_table_kernel(
    const float2* __restrict__ t, h2* __restrict__ o, int total)
{
    int i = blockIdx.x * 256 + threadIdx.x;
    if (i < total) {
        float2 v = t[i];
        h2 r; r[0] = (_Float16)v.x; r[1] = (_Float16)v.y;
        o[i] = r;
    }
}

// ---------------- Kernel A: hash-grid encode -> enc2 [16][N] h2 ----------------
// Level-major blocks: blockIdx.y = level (slow-varying in dispatch order), so
// concurrently-resident blocks share 1-2 levels -> working set fits per-XCD L2.
template <typename TT>
__global__ __launch_bounds__(256) void encode_kernel(
    const float* __restrict__ xs, const TT* __restrict__ table,
    h2* __restrict__ enc2, Levels lv, int N)
{
    __shared__ float sx[768];          // 256 points * xyz
    __shared__ float s_scale[16];
    __shared__ int   s_res[16];

    const int i0 = blockIdx.x * 256;
    for (int t = threadIdx.x; t < 768; t += 256) sx[t] = xs[(size_t)i0 * 3 + t];
    if (threadIdx.x < 16) {
        s_scale[threadIdx.x] = lv.scale[threadIdx.x];
        s_res[threadIdx.x]   = lv.res[threadIdx.x];
    }
    __syncthreads();

    const int l = blockIdx.y;          // block-uniform level
    const int i = i0 + threadIdx.x;
    if (i >= N) return;

    const float px = sx[threadIdx.x * 3 + 0];
    const float py = sx[threadIdx.x * 3 + 1];
    const float pz = sx[threadIdx.x * 3 + 2];
    const float s  = s_scale[l];
    const int  res = s_res[l];

    float fx = px * s + 0.5f, fy = py * s + 0.5f, fz = pz * s + 0.5f;
    float gx = floorf(fx), gy = floorf(fy), gz = floorf(fz);
    float wx = fx - gx, wy = fy - gy, wz = fz - gz;
    int cx = (int)gx, cy = (int)gy, cz = (int)gz;

    unsigned idx[8];
    if ((lv.dense_mask >> l) & 1u) {   // uniform branch (scalar)
        int r1 = res - 1;
        int x0 = min(cx, r1), x1 = min(cx + 1, r1);
        int y0 = min(cy, r1), y1 = min(cy + 1, r1);
        int z0 = min(cz, r1), z1 = min(cz + 1, r1);
        int yr0 = y0 * res, yr1 = y1 * res;
        int rr = res * res;
        int zr0 = z0 * rr, zr1 = z1 * rr;
        // corner c: xo=c>>2, yo=(c>>1)&1, zo=c&1
        idx[0] = x0 + yr0 + zr0;
        idx[1] = x0 + yr0 + zr1;
        idx[2] = x0 + yr1 + zr0;
        idx[3] = x0 + yr1 + zr1;
        idx[4] = x1 + yr0 + zr0;
        idx[5] = x1 + yr0 + zr1;
        idx[6] = x1 + yr1 + zr0;
        idx[7] = x1 + yr1 + zr1;
    } else {
        unsigned hx0 = (unsigned)cx, hx1 = (unsigned)(cx + 1);
        unsigned hy0 = (unsigned)cy * 2654435761u, hy1 = (unsigned)(cy + 1) * 2654435761u;
        unsigned hz0 = (unsigned)cz * 805459861u,  hz1 = (unsigned)(cz + 1) * 805459861u;
        idx[0] = (hx0 ^ hy0 ^ hz0) & (T_SIZE - 1);
        idx[1] = (hx0 ^ hy0 ^ hz1) & (T_SIZE - 1);
        idx[2] = (hx0 ^ hy1 ^ hz0) & (T_SIZE - 1);
        idx[3] = (hx0 ^ hy1 ^ hz1) & (T_SIZE - 1);
        idx[4] = (hx1 ^ hy0 ^ hz0) & (T_SIZE - 1);
        idx[5] = (hx1 ^ hy0 ^ hz1) & (T_SIZE - 1);
        idx[6] = (hx1 ^ hy1 ^ hz0) & (T_SIZE - 1);
        idx[7] = (hx1 ^ hy1 ^ hz1) & (T_SIZE - 1);
    }

    const TT* tl = table + (size_t)l * T_SIZE;
    float2 v0 = load_pair(tl + idx[0]);
    float2 v1 = load_pair(tl + idx[1]);
    float2 v2 = load_pair(tl + idx[2]);
    float2 v3 = load_pair(tl + idx[3]);
    float2 v4 = load_pair(tl + idx[4]);
    float2 v5 = load_pair(tl + idx[5]);
    float2 v6 = load_pair(tl + idx[6]);
    float2 v7 = load_pair(tl + idx[7]);

    float wx0 = 1.f - wx, wy0 = 1.f - wy, wz0 = 1.f - wz;
    float wxy00 = wx0 * wy0, wxy01 = wx0 * wy, wxy10 = wx * wy0, wxy11 = wx * wy;
    float f0 = 0.f, f1 = 0.f, wc;
    wc = wxy00 * wz0; f0 += wc * v0.x; f1 += wc * v0.y;
    wc = wxy00 * wz;  f0 += wc * v1.x; f1 += wc * v1.y;
    wc = wxy01 * wz0; f0 += wc * v2.x; f1 += wc * v2.y;
    wc = wxy01 * wz;  f0 += wc * v3.x; f1 += wc * v3.y;
    wc = wxy10 * wz0; f0 += wc * v4.x; f1 += wc * v4.y;
    wc = wxy10 * wz;  f0 += wc * v5.x; f1 += wc * v5.y;
    wc = wxy11 * wz0; f0 += wc * v6.x; f1 += wc * v6.y;
    wc = wxy11 * wz;  f0 += wc * v7.x; f1 += wc * v7.y;

    h2 r;
    r[0] = (_Float16)f0;
    r[1] = (_Float16)f1;
    enc2[(size_t)l * N + i] = r;       // coalesced 4B store per lane
}

// ---------------- Kernel B: fused MLP via f16 MFMA ----------------
// enc2 is level-major [16][N] h2. A-layout: A[m=lane&15][k=quad*8+j];
// D-layout: D[row=quad*4+r][col=lane&15].
__global__ __launch_bounds__(256) void mlp_kernel(
    const h2* __restrict__ enc2,
    const float* __restrict__ w1, const float* __restrict__ w2,
    const float* __restrict__ w3, const float* __restrict__ w4,
    float* __restrict__ out, int tiles, int N)
{
    constexpr int W1R = 40;
    constexpr int W2R = 72;
    constexpr int AR  = 72;
    __shared__ _Float16 sW1[64 * W1R];
    __shared__ _Float16 sW2[64 * W2R];
    __shared__ _Float16 sW3[64 * W2R];
    __shared__ float    sW4[64];
    __shared__ _Float16 sAct[256 * AR];

    const int tid = threadIdx.x;
    for (int i = tid; i < 64 * 32; i += 256) sW1[(i >> 5) * W1R + (i & 31)] = (_Float16)w1[i];
    for (int i = tid; i < 64 * 64; i += 256) sW2[(i >> 6) * W2R + (i & 63)] = (_Float16)w2[i];
    for (int i = tid; i < 64 * 64; i += 256) sW3[(i >> 6) * W2R + (i & 63)] = (_Float16)w3[i];
    if (tid < 64) sW4[tid] = w4[tid];
    __syncthreads();

    const int wave = tid >> 6;
    const int lane = tid & 63;
    const int lrow = lane & 15;
    const int quad = lane >> 4;
    const int waveRow = wave * 64;
    const f4 zero = {0.f, 0.f, 0.f, 0.f};

    // loop-invariant weight fragments
    h8 b1[4];
#pragma unroll
    for (int tn = 0; tn < 4; ++tn)
        b1[tn] = *(const h8*)&sW1[(lrow + 16 * tn) * W1R + quad * 8];
    h8 b2[2][4], b3[2][4];
#pragma unroll
    for (int kh = 0; kh < 2; ++kh)
#pragma unroll
        for (int tn = 0; tn < 4; ++tn) {
            b2[kh][tn] = *(const h8*)&sW2[(lrow + 16 * tn) * W2R + kh * 32 + quad * 8];
            b3[kh][tn] = *(const h8*)&sW3[(lrow + 16 * tn) * W2R + kh * 32 + quad * 8];
        }

    for (int it = 0; it < tiles; ++it) {
        const int blockPt = (blockIdx.x * tiles + it) * 256;

        // ---- Layer 1: enc2(level-major) @ w1^T ----
#pragma unroll
        for (int t = 0; t < 4; ++t) {
            const int rowg = blockPt + waveRow + t * 16 + lrow;
            h8 a;
#pragma unroll
            for (int d = 0; d < 4; ++d) {
                h2 p = enc2[(size_t)(4 * quad + d) * N + rowg];   // 4B coalesced
                a[2 * d]     = p[0];
                a[2 * d + 1] = p[1];
            }
#pragma unroll
            for (int tn = 0; tn < 4; ++tn) {
                f4 acc = __builtin_amdgcn_mfma_f32_16x16x32_f16(a, b1[tn], zero, 0, 0, 0);
#pragma unroll
                for (int r = 0; r < 4; ++r) {
                    int prow = waveRow + t * 16 + quad * 4 + r;
                    sAct[prow * AR + tn * 16 + lrow] = (_Float16)softplus10(acc[r]);
                }
            }
        }
        __syncthreads();

        // ---- Layers 2 & 3 ----
#pragma unroll
        for (int layer = 0; layer < 2; ++layer) {
#pragma unroll
            for (int t = 0; t < 4; ++t) {
                const int arow = (waveRow + t * 16 + lrow) * AR;
                h8 a0 = *(const h8*)&sAct[arow + quad * 8];
                h8 a1 = *(const h8*)&sAct[arow + 32 + quad * 8];
                f4 accs[4];
#pragma unroll
                for (int tn = 0; tn < 4; ++tn) {
                    f4 acc = __builtin_amdgcn_mfma_f32_16x16x32_f16(
                        a0, layer ? b3[0][tn] : b2[0][tn], zero, 0, 0, 0);
                    acc = __builtin_amdgcn_mfma_f32_16x16x32_f16(
                        a1, layer ? b3[1][tn] : b2[1][tn], acc, 0, 0, 0);
                    accs[tn] = acc;
                }
#pragma unroll
                for (int tn = 0; tn < 4; ++tn)
#pragma unroll
                    for (int r = 0; r < 4; ++r)
                        sAct[(waveRow + t * 16 + quad * 4 + r) * AR + tn * 16 + lrow] =
                            (_Float16)softplus10(accs[tn][r]);
            }
            __syncthreads();
        }

        // ---- Layer 4: per-thread dot with w4 ----
        float sum = 0.f;
#pragma unroll
        for (int k8 = 0; k8 < 8; ++k8) {
            h8 a = *(const h8*)&sAct[tid * AR + k8 * 8];
#pragma unroll
            for (int j = 0; j < 8; ++j) sum += (float)a[j] * sW4[k8 * 8 + j];
        }
        out[blockPt + tid] = sum;
        __syncthreads();   // sAct reused next iteration
    }
}

extern "C" void kernel_launch(void* const* d_in, const int* in_sizes, int n_in,
                              void* d_out, int out_size, void* d_ws, size_t ws_size,
                              hipStream_t stream) {
    const float* x     = (const float*)d_in[0];
    const float* table = (const float*)d_in[1];
    const float* w1    = (const float*)d_in[2];
    const float* w2    = (const float*)d_in[3];
    const float* w3    = (const float*)d_in[4];
    const float* w4    = (const float*)d_in[5];
    float* out = (float*)d_out;
    const int N = in_sizes[0] / 3;                 // 1<<20

    Levels lv;
    lv.dense_mask = 0;
    const double pls = exp2(log2(2048.0 / 16.0) / 15.0);
    const double lg  = log2(pls);
    for (int l = 0; l < 16; ++l) {
        double sc = exp2((double)l * lg) * 16.0 - 1.0;
        int res = (int)ceil(sc) + 1;
        lv.scale[l] = (float)sc;
        lv.res[l]   = res;
        if ((long long)res * res * res <= (long long)T_SIZE) lv.dense_mask |= (1u << l);
    }

    const size_t encBytes   = (size_t)16 * N * 4;        // [16][N] h2 = 64 MB
    const size_t tableBytes = (size_t)16 * T_SIZE * 4;   // f16 table = 33.5 MB
    h2* enc2 = (h2*)d_ws;

    const int ptBlocks = (N + 255) / 256;                // 4096
    dim3 encGrid(ptBlocks, 16);                          // y = level, slow-varying

    if (ws_size >= encBytes + tableBytes) {
        h2* table16 = (h2*)((char*)d_ws + encBytes);
        const int total = 16 * T_SIZE;
        hipLaunchKernelGGL(convert_table_kernel, dim3((total + 255) / 256), dim3(256), 0,
                           stream, (const float2*)table, table16, total);
        hipLaunchKernelGGL((encode_kernel<h2>), encGrid, dim3(256), 0, stream,
                           x, (const h2*)table16, enc2, lv, N);
    } else {
        hipLaunchKernelGGL((encode_kernel<float2>), encGrid, dim3(256), 0, stream,
                           x, (const float2*)table, enc2, lv, N);
    }

    const int mlpBlocks = 512;                           // 2 blocks/CU
    const int tiles = N / 256 / mlpBlocks;               // 8
    hipLaunchKernelGGL(mlp_kernel, dim3(mlpBlocks), dim3(256), 0, stream,
                       enc2, w1, w2, w3, w4, out, tiles, N);
}